// Round 15
// baseline (266.942 us; speedup 1.0000x reference)
//
#include <hip/hip_runtime.h>

// Problem constants
#define B_ 8
#define N_ 2048
#define T_ 12
#define F_ 64
#define NT 24576    // N_*T_
#define CH 192      // 3 * 64 output channels
#define C_ 768      // 64 * 12 rows per diffusion GEMM B-operand

typedef __bf16 bf16x8 __attribute__((ext_vector_type(8)));
typedef float f32x4 __attribute__((ext_vector_type(4)));
typedef float f32x16 __attribute__((ext_vector_type(16)));

typedef const __attribute__((address_space(1))) unsigned int as1_uint;
typedef __attribute__((address_space(3))) unsigned int as3_uint;

__device__ __forceinline__ void gload16(const void* g, void* l) {
  __builtin_amdgcn_global_load_lds((as1_uint*)g, (as3_uint*)l, 16, 0, 0);
}

__device__ __forceinline__ unsigned short f2bf(float f) {
  unsigned int u = __float_as_uint(f);
  u += 0x7FFFu + ((u >> 16) & 1u);   // RNE
  return (unsigned short)(u >> 16);
}

__device__ __forceinline__ float bf2f(unsigned short u) {
  return __uint_as_float(((unsigned int)u) << 16);
}

__device__ __forceinline__ float leaky(float v) {
  return v >= 0.0f ? v : 0.01f * v;
}

// ---------------------------------------------------------------------------
// convert_rs_k: adj fp32 -> adjb bf16 AND rs1[b][n] = rowsum(adj).
// ---------------------------------------------------------------------------
__global__ __launch_bounds__(256) void convert_rs_k(const float* __restrict__ adj,
                                                    unsigned short* __restrict__ adjb,
                                                    float* __restrict__ rs1) {
  const int row = blockIdx.x;               // b*2048 + n
  const int tid = threadIdx.x;
  const int lane = tid & 63;
  const int wave = tid >> 6;
  const float4* src = reinterpret_cast<const float4*>(adj + (size_t)row * N_);
  ushort4* dst = reinterpret_cast<ushort4*>(adjb + (size_t)row * N_);

  float s = 0.0f;
#pragma unroll
  for (int i = tid; i < 512; i += 256) {
    const float4 v = src[i];
    ushort4 u;
    u.x = f2bf(v.x); u.y = f2bf(v.y); u.z = f2bf(v.z); u.w = f2bf(v.w);
    dst[i] = u;
    s += v.x + v.y + v.z + v.w;
  }
#pragma unroll
  for (int o = 32; o; o >>= 1) s += __shfl_xor(s, o);
  __shared__ float red[4];
  if (lane == 0) red[wave] = s;
  __syncthreads();
  if (tid == 0) rs1[row] = red[0] + red[1] + red[2] + red[3];
}

// ---------------------------------------------------------------------------
// rs2_k: rs2 = adjb @ rs1 (per-batch GEMV).
// ---------------------------------------------------------------------------
__global__ __launch_bounds__(256) void rs2_k(const unsigned short* __restrict__ adjb,
                                             const float* __restrict__ rs1,
                                             float* __restrict__ rs2) {
  const int row = blockIdx.x;
  const int b = row >> 11;
  const int tid = threadIdx.x;
  const int lane = tid & 63;
  const int wave = tid >> 6;
  const ushort4* src = reinterpret_cast<const ushort4*>(adjb + (size_t)row * N_);
  const float* r1 = rs1 + ((size_t)b << 11);

  float s = 0.0f;
#pragma unroll
  for (int i = tid; i < 512; i += 256) {
    const ushort4 a = src[i];
    const int m = i * 4;
    s += bf2f(a.x) * r1[m] + bf2f(a.y) * r1[m + 1]
       + bf2f(a.z) * r1[m + 2] + bf2f(a.w) * r1[m + 3];
  }
#pragma unroll
  for (int o = 32; o; o >>= 1) s += __shfl_xor(s, o);
  __shared__ float red[4];
  if (lane == 0) red[wave] = s;
  __syncthreads();
  if (tid == 0) rs2[row] = red[0] + red[1] + red[2] + red[3];
}

// ---------------------------------------------------------------------------
// convertX_k: x fp32 [b][f][n][t] -> Xt bf16 [b][(f*12+t)][n].
// ---------------------------------------------------------------------------
__global__ __launch_bounds__(256) void convertX_k(const float* __restrict__ x,
                                                  unsigned short* __restrict__ Xt) {
  __shared__ float xl[T_][260];
  const int tid = threadIdx.x;
  const int n0 = blockIdx.x * 256;
  const int f = blockIdx.y;
  const int b = blockIdx.z;

  const float* src = x + (((size_t)b * F_ + f) * N_ + n0 + tid) * T_;
  float4 v0 = *reinterpret_cast<const float4*>(src);
  float4 v1 = *reinterpret_cast<const float4*>(src + 4);
  float4 v2 = *reinterpret_cast<const float4*>(src + 8);
  xl[0][tid] = v0.x;  xl[1][tid] = v0.y;  xl[2][tid] = v0.z;  xl[3][tid] = v0.w;
  xl[4][tid] = v1.x;  xl[5][tid] = v1.y;  xl[6][tid] = v1.z;  xl[7][tid] = v1.w;
  xl[8][tid] = v2.x;  xl[9][tid] = v2.y;  xl[10][tid] = v2.z; xl[11][tid] = v2.w;
  __syncthreads();
#pragma unroll
  for (int t = 0; t < T_; ++t)
    Xt[((size_t)b * C_ + f * T_ + t) * N_ + n0 + tid] = f2bf(xl[t][tid]);
}

// ---------------------------------------------------------------------------
// stage_wt + p0_k + pT_k (unchanged)
// ---------------------------------------------------------------------------
__device__ __forceinline__ void stage_wt(const float* __restrict__ W,
                                         unsigned short* Wt, int tid) {
  const int f = tid >> 2;
  const int q = tid & 3;
  const float4* row = reinterpret_cast<const float4*>(W + f * 64 + q * 16);
#pragma unroll
  for (int v4 = 0; v4 < 4; ++v4) {
    float4 v = row[v4];
    const int ob = q * 16 + v4 * 4;
    Wt[(ob + 0) * 72 + f] = f2bf(v.x);
    Wt[(ob + 1) * 72 + f] = f2bf(v.y);
    Wt[(ob + 2) * 72 + f] = f2bf(v.z);
    Wt[(ob + 3) * 72 + f] = f2bf(v.w);
  }
}

__global__ __launch_bounds__(256) void p0_k(const float* __restrict__ x,
                                            const float* __restrict__ W0,
                                            const float* __restrict__ bia0,
                                            float* __restrict__ out) {
  __shared__ unsigned short Wt[64 * 72];
  __shared__ float bias[64];
  const int tid = threadIdx.x;
  stage_wt(W0, Wt, tid);
  if (tid < 64) bias[tid] = bia0[tid];
  __syncthreads();

  const int lane = tid & 63;
  const int wave = tid >> 6;
  const int b = blockIdx.y;
  const int e = blockIdx.x * 64 + wave * 16 + (lane & 15);
  const int fgrp = (lane >> 4) * 8;
  const float* xb = x + (size_t)b * F_ * NT;

  bf16x8 xf[2];
#pragma unroll
  for (int kf = 0; kf < 2; ++kf)
#pragma unroll
    for (int j = 0; j < 8; ++j)
      xf[kf][j] = (__bf16)xb[(size_t)(fgrp + kf * 32 + j) * NT + e];

  float* outb = out + (size_t)b * CH * NT;
#pragma unroll
  for (int ob = 0; ob < 4; ++ob) {
    f32x4 acc = {};
#pragma unroll
    for (int kf = 0; kf < 2; ++kf) {
      bf16x8 af = *reinterpret_cast<const bf16x8*>(
          &Wt[(ob * 16 + (lane & 15)) * 72 + kf * 32 + fgrp]);
      acc = __builtin_amdgcn_mfma_f32_16x16x32_bf16(af, xf[kf], acc, 0, 0, 0);
    }
#pragma unroll
    for (int r = 0; r < 4; ++r) {
      const int o = ob * 16 + (lane >> 4) * 4 + r;
      outb[(size_t)o * NT + e] = leaky(acc[r] + bias[o]);
    }
  }
}

__global__ __launch_bounds__(256) void pT_k(const unsigned short* __restrict__ Yt,
                                            const float* __restrict__ W,
                                            const float* __restrict__ bia,
                                            const float* __restrict__ rs,
                                            float* __restrict__ out,
                                            const int ocb) {
  __shared__ unsigned short Wt[64 * 72];
  __shared__ float bias[64];
  const int tid = threadIdx.x;
  stage_wt(W, Wt, tid);
  if (tid < 64) bias[tid] = bia[tid];
  __syncthreads();

  const int lane = tid & 63;
  const int wave = tid >> 6;
  const int b = blockIdx.y;
  const int n = blockIdx.x * 16 + (lane & 15);
  const int fgrp = (lane >> 4) * 8;
  const __bf16* Yb = reinterpret_cast<const __bf16*>(Yt + (size_t)b * C_ * N_);
  const float rsv = rs[((size_t)b << 11) + n];
  float* outb = out + (size_t)b * CH * NT;

#pragma unroll
  for (int it = 0; it < 3; ++it) {
    const int t = wave * 3 + it;

    bf16x8 xf[2];
#pragma unroll
    for (int kf = 0; kf < 2; ++kf)
#pragma unroll
      for (int j = 0; j < 8; ++j)
        xf[kf][j] = Yb[(size_t)((kf * 32 + fgrp + j) * T_ + t) * N_ + n];

#pragma unroll
    for (int ob = 0; ob < 4; ++ob) {
      f32x4 acc = {};
#pragma unroll
      for (int kf = 0; kf < 2; ++kf) {
        bf16x8 af = *reinterpret_cast<const bf16x8*>(
            &Wt[(ob * 16 + (lane & 15)) * 72 + kf * 32 + fgrp]);
        acc = __builtin_amdgcn_mfma_f32_16x16x32_bf16(af, xf[kf], acc, 0, 0, 0);
      }
#pragma unroll
      for (int r = 0; r < 4; ++r) {
        const int o = ob * 16 + (lane >> 4) * 4 + r;
        outb[(size_t)(ocb + o) * NT + n * T_ + t] = leaky(acc[r] + rsv * bias[o]);
      }
    }
  }
}

// ---------------------------------------------------------------------------
// gemmB_k: 32x32x16 MFMA diffusion GEMM (2x operand intensity vs 16x16x32).
// C[n][c] = sum_m adj[b][n][m] * Bt[b][c][m],  K = 2048, BK = 64.
// Tile 128x192, 4 waves (2M x 2N), wave 64x96 = acc[2][3] f32x16.
// Per k16-step: 2 A-frags + 3 B-frags (5 ds_read_b128) feed 6 MFMA --
// 16 FLOP per LDS byte vs 8 for the 16x16x32 shape; staging bytes per
// output also halve (128x192 tile from 40KB vs 128x96 from 28KB).
// Same single-buffer 2-__syncthreads structure as round-14 gemmF.
//
// LDS [row][64 shorts], granule(16B)-XOR: LDS(r,g) holds global(r, g^(r&7)).
//  - staging: linear dest; per-lane GLOBAL granule pre-swizzled (l&7)^(l>>3)
//  - frag read (32 rows): row = base+(l&31), gran = 2s+(l>>5),
//    g_eff = gran ^ (l&7). Row stride = 128B spans all 32 banks, so bank =
//    f(g_eff) only; each 8-lane group covers all 32 banks once -> 8-cy
//    floor, zero conflicts.
// C/D 32x32 layout (m74/m101): col = lane&31, row = (reg&3)+8*(reg>>2)
// +4*(lane>>5).
// grid 512 = 8 b x (16 n x 4 c) = 2 blocks/CU (80KB LDS); blockIdx&7 = XCD.
// Epilogue: Ht[c][n] bf16 transposed.
// ---------------------------------------------------------------------------
__global__ __launch_bounds__(256, 2) void gemmB_k(
    const unsigned short* __restrict__ adjb,
    const unsigned short* __restrict__ Bt,
    unsigned short* __restrict__ Ht)
{
  __shared__ __align__(16) unsigned short lds[20480];  // A[128][64] + B[192][64]

  const int tid  = threadIdx.x;
  const int lane = tid & 63;
  const int wave = tid >> 6;     // 0..3
  const int wm = wave >> 1;      // 0..1  M half (64 rows)
  const int wn = wave & 1;       // 0..1  N half (96 cols)

  const int b  = blockIdx.x & 7;            // batch == XCD
  const int j  = blockIdx.x >> 3;           // 0..63
  const int n0 = (j & 15) * 128;
  const int c0 = (j >> 4) * 192;

  const unsigned short* A  = adjb + (size_t)b * N_ * N_;
  const unsigned short* Bm = Bt   + (size_t)b * C_ * N_;

  // staging: per gload, lane l -> row base+(l>>3), LDS granule l&7 (linear);
  // GLOBAL source granule pre-swizzled = (l&7)^(l>>3).
  const int swz = ((lane & 7) ^ (lane >> 3)) * 8;   // shorts
  const unsigned short* aSt = A + (size_t)(n0 + wave * 32 + (lane >> 3)) * N_ + swz;
  const unsigned short* bSt = Bm + (size_t)(c0 + wave * 48 + (lane >> 3)) * N_ + swz;

  // fragment read lane constants
  const int l31 = lane & 31;
  const int x7  = lane & 7;
  const int hi  = lane >> 5;           // 0..1 (k-granule bit0 pre-XOR)
  const int sh  = (lane >> 1) & 3;     // x7 >> 1 (bits 1-2 of the XOR)
  const int e0  = hi ^ (x7 & 1);       // bit0 of g_eff
  const int aBase0 = (wm * 64 + l31) * 64;          // + m*2048 + g_eff*8
  const int bBase0 = 8192 + (wn * 96 + l31) * 64;   // + nf*2048 + g_eff*8

  f32x16 acc[2][3] = {};

#define STG(KT) \
  gload16(aSt + (KT) * 64,            lds + wave * 2048); \
  gload16(aSt + 8 * N_ + (KT) * 64,   lds + wave * 2048 + 512); \
  gload16(aSt + 16 * N_ + (KT) * 64,  lds + wave * 2048 + 1024); \
  gload16(aSt + 24 * N_ + (KT) * 64,  lds + wave * 2048 + 1536); \
  gload16(bSt + (KT) * 64,            lds + 8192 + wave * 3072); \
  gload16(bSt + 8 * N_ + (KT) * 64,   lds + 8192 + wave * 3072 + 512); \
  gload16(bSt + 16 * N_ + (KT) * 64,  lds + 8192 + wave * 3072 + 1024); \
  gload16(bSt + 24 * N_ + (KT) * 64,  lds + 8192 + wave * 3072 + 1536); \
  gload16(bSt + 32 * N_ + (KT) * 64,  lds + 8192 + wave * 3072 + 2048); \
  gload16(bSt + 40 * N_ + (KT) * 64,  lds + 8192 + wave * 3072 + 2560);

  // ---- prologue: stage tile 0
  STG(0)

#pragma unroll 1
  for (int kt = 0; kt < 32; ++kt) {
    __syncthreads();             // tile kt staged (vmcnt drained) & visible
#pragma unroll
    for (int s = 0; s < 4; ++s) {
      const int ge = ((((s) ^ sh) << 1) | e0) * 8;
      bf16x8 af[2], bfv[3];
#pragma unroll
      for (int m = 0; m < 2; ++m)
        af[m] = *(const bf16x8*)(lds + aBase0 + m * 2048 + ge);
#pragma unroll
      for (int nf = 0; nf < 3; ++nf)
        bfv[nf] = *(const bf16x8*)(lds + bBase0 + nf * 2048 + ge);
#pragma unroll
      for (int m = 0; m < 2; ++m)
#pragma unroll
        for (int nf = 0; nf < 3; ++nf)
          acc[m][nf] = __builtin_amdgcn_mfma_f32_32x32x16_bf16(
              af[m], bfv[nf], acc[m][nf], 0, 0, 0);
    }
    __syncthreads();             // all waves done reading tile kt
    if (kt + 1 < 32) { STG(kt + 1) }
  }

  // ---- epilogue: Ht[c][n] bf16. D frag (32x32): col = lane&31,
  // row = (reg&3) + 8*(reg>>2) + 4*(lane>>5)
  unsigned short* Hb = Ht + (size_t)b * C_ * N_;
#pragma unroll
  for (int m = 0; m < 2; ++m) {
#pragma unroll
    for (int nf = 0; nf < 3; ++nf) {
      const int c = c0 + wn * 96 + nf * 32 + l31;
#pragma unroll
      for (int q = 0; q < 4; ++q) {
        const int nb = n0 + wm * 64 + m * 32 + q * 8 + 4 * hi;
        ushort4 u;
        u.x = f2bf(acc[m][nf][q * 4 + 0]);
        u.y = f2bf(acc[m][nf][q * 4 + 1]);
        u.z = f2bf(acc[m][nf][q * 4 + 2]);
        u.w = f2bf(acc[m][nf][q * 4 + 3]);
        *reinterpret_cast<ushort4*>(&Hb[(size_t)c * N_ + nb]) = u;
      }
    }
  }
#undef STG
}

// ---------------------------------------------------------------------------
// Workspace layout (bytes):
//   adjb : [0, 67108864)            8*2048*2048 bf16
//   R1   : [67108864, 92274688)     Xt, then Y2t   (8*768*2048 bf16)
//   R2   : [92274688, 117440512)    Yt
//   rs1  : [117440512, 117506048)   8*2048 fp32
//   rs2  : [117506048, 117571584)   8*2048 fp32
// ---------------------------------------------------------------------------
extern "C" void kernel_launch(void* const* d_in, const int* in_sizes, int n_in,
                              void* d_out, int out_size, void* d_ws, size_t ws_size,
                              hipStream_t stream) {
  const float* x   = (const float*)d_in[0];
  const float* adj = (const float*)d_in[1];
  const float* W0  = (const float*)d_in[2];
  const float* b0  = (const float*)d_in[3];
  const float* W1  = (const float*)d_in[4];
  const float* b1  = (const float*)d_in[5];
  const float* W2  = (const float*)d_in[6];
  const float* b2  = (const float*)d_in[7];
  float* out = (float*)d_out;

  char* ws = (char*)d_ws;
  unsigned short* adjb = (unsigned short*)ws;
  unsigned short* R1   = (unsigned short*)(ws + 67108864);   // Xt -> Y2t
  unsigned short* R2   = (unsigned short*)(ws + 92274688);   // Yt
  float* rs1 = (float*)(ws + 117440512);
  float* rs2 = (float*)(ws + 117506048);

  // 1) adj -> bf16 + rowsums rs1
  hipLaunchKernelGGL(convert_rs_k, dim3(B_ * N_), dim3(256), 0, stream,
                     adj, adjb, rs1);

  // 2) x -> Xt bf16 [(f,t)][n]
  hipLaunchKernelGGL(convertX_k, dim3(N_ / 256, F_, B_), dim3(256), 0, stream,
                     x, R1);

  // 3) p=0: out[0:64) = leaky(x.W0 + b0)
  hipLaunchKernelGGL(p0_k, dim3(NT / 64, B_), dim3(256), 0, stream,
                     x, W0, b0, out);

  // 4) Yt = (A @ X)^T
  hipLaunchKernelGGL(gemmB_k, dim3(512), dim3(256), 0, stream,
                     adjb, R1, R2);

  // 5) rs2 = A @ rs1
  hipLaunchKernelGGL(rs2_k, dim3(B_ * N_), dim3(256), 0, stream,
                     adjb, rs1, rs2);

  // 6) p=1: out[64:128) = leaky(Y.W1 + rs1*b1)
  hipLaunchKernelGGL(pT_k, dim3(N_ / 16, B_), dim3(256), 0, stream,
                     R2, W1, b1, rs1, out, 64);

  // 7) Y2t = (A @ Y)^T
  hipLaunchKernelGGL(gemmB_k, dim3(512), dim3(256), 0, stream,
                     adjb, R2, R1);

  // 8) p=2: out[128:192) = leaky(Y2.W2 + rs2*b2)
  hipLaunchKernelGGL(pT_k, dim3(N_ / 16, B_), dim3(256), 0, stream,
                     R1, W2, b2, rs2, out, 128);
}